// Round 9
// baseline (198.349 us; speedup 1.0000x reference)
//
#include <hip/hip_runtime.h>
#include <hip/hip_bf16.h>

#define T_TOK   2048
#define NEXP    8
#define HDIM    1024
#define IDIM    768
#define TOPK    2
#define NASSIGN (T_TOK*TOPK)
#define MT      128
#define MAX_TILES 40
#define SLOT_PAD 5120   // MAX_TILES*128

typedef unsigned short u16;
typedef unsigned int   u32;

typedef __bf16 bf16x8 __attribute__((ext_vector_type(8)));
typedef float  f32x4  __attribute__((ext_vector_type(4)));

struct Meta {
  int n_tiles;
  int _pad[15];
  int tile_e[80];
  int tile_m[80];
  int tile_n[80];
};

__device__ __forceinline__ u16 f2bf(float f) {
  u32 x = __float_as_uint(f);
  return (u16)((x + 0x7fffu + ((x >> 16) & 1u)) >> 16);   // RNE, inputs finite
}

// pack two float4 (8 consecutive fp32) -> int4 of 8 bf16
__device__ __forceinline__ int4 cvt8r(float4 a, float4 b) {
  union { u16 u[8]; int4 v; } r;
  r.u[0] = f2bf(a.x); r.u[1] = f2bf(a.y); r.u[2] = f2bf(a.z); r.u[3] = f2bf(a.w);
  r.u[4] = f2bf(b.x); r.u[5] = f2bf(b.y); r.u[6] = f2bf(b.z); r.u[7] = f2bf(b.w);
  return r.v;
}

__device__ __forceinline__ bf16x8 asbf(int4 v) {
  return __builtin_bit_cast(bf16x8, v);
}

// async global->LDS, 16B per lane; lds ptr wave-uniform (lane scatters +16B each)
__device__ __forceinline__ void gll(const void* g, void* l) {
  __builtin_amdgcn_global_load_lds(
      (const __attribute__((address_space(1))) u32*)g,
      (__attribute__((address_space(3))) u32*)l, 16, 0, 0);
}

// ---------------- prep: routing (block 0) + zero d_out ----------------
// No weight/hidden conversion anymore: conversion is fused into the GEMM staging.
__global__ __launch_bounds__(256) void prep_k(
    const int* __restrict__ topk, const float* __restrict__ tw,
    Meta* __restrict__ meta, int* __restrict__ slot_token, float* __restrict__ slot_w,
    float* __restrict__ out) {
  int tid = threadIdx.x;
  if (blockIdx.x == 0) {
    __shared__ int s_cnt[NEXP], s_off[NEXP], s_cur[NEXP];
    if (tid < NEXP) { s_cnt[tid] = 0; s_cur[tid] = 0; }
    __syncthreads();
    for (int i = tid; i < NASSIGN; i += 256)
      atomicAdd(&s_cnt[topk[i]], 1);
    __syncthreads();
    if (tid == 0) {
      int acc = 0, nt = 0;
      for (int e = 0; e < NEXP; ++e) {
        s_off[e] = acc;
        int c = s_cnt[e];
        for (int mb = 0; mb < c; mb += MT) {
          meta->tile_e[nt] = e;
          meta->tile_m[nt] = acc + mb;
          meta->tile_n[nt] = (c - mb) < MT ? (c - mb) : MT;
          ++nt;
        }
        acc += c;
      }
      meta->n_tiles = nt;
    }
    __syncthreads();
    for (int i = tid; i < NASSIGN; i += 256) {
      int e = topk[i];
      int p = s_off[e] + atomicAdd(&s_cur[e], 1);
      slot_token[p] = i / TOPK;
      slot_w[p]     = tw[i];
    }
    for (int i = NASSIGN + tid; i < SLOT_PAD; i += 256) {  // pad: token 0, weight 0
      slot_token[i] = 0;
      slot_w[i]     = 0.0f;
    }
    return;
  }
  // zero d_out: 524,288 int4 = 256 blocks * 256 threads * 8
  size_t t = ((size_t)blockIdx.x - 1) * 256 + tid;
  int4 z = {0, 0, 0, 0};
  #pragma unroll
  for (int k = 0; k < 8; ++k)
    *(int4*)(out + (t + (size_t)k * 65536) * 4) = z;
}

// ---------------- GEMM1 (fused cvt): h = silu(x@Wg^T) * (x@Wu^T) * route_w ----
// 128x128 tiles, 512 threads, 2-slot LDS (96 KB), reg-staged fp32->bf16.
// grid 240 = 40 tiles x 6 n-stripes, XCD-chunked.
__global__ __launch_bounds__(512, 1) void gemm1_k(
    const float* __restrict__ hs, const float* __restrict__ gup,
    const Meta* __restrict__ meta, const int* __restrict__ slot_token,
    const float* __restrict__ slot_w, u16* __restrict__ hbuf) {
  int bid = blockIdx.x;
  int wg = (bid & 7) * 30 + (bid >> 3);   // 240/8 = 30 per XCD
  int tile = wg / 6, y = wg % 6;
  if (tile >= meta->n_tiles) return;
  int e = meta->tile_e[tile], mbase = meta->tile_m[tile], nrows = meta->tile_n[tile];
  int n0 = y * 128;

  __shared__ int4 lds[2][3][1024];   // [slot][A|Bg|Bu], 128x64 bf16 each; 96 KB
  int tid = threadIdx.x, lane = tid & 63, w = tid >> 6;
  int wm = w >> 2, wn = w & 3;       // wave grid 2(M) x 4(N); wave tile 64x32
  f32x4 accg[4][2] = {}, accu[4][2] = {};

  // this thread stages rows r0 and r0+64 at fp32 column s*8 of each 64-wide K-tile
  int r0 = tid >> 3, s = tid & 7;
  int tok0 = slot_token[mbase + r0];
  int tok1 = slot_token[mbase + r0 + 64];
  const float* A0 = hs + (size_t)tok0 * HDIM + s * 8;
  const float* A1 = hs + (size_t)tok1 * HDIM + s * 8;
  const float* G0 = gup + (size_t)e * (2 * IDIM) * HDIM + (size_t)(n0 + r0) * HDIM + s * 8;
  const float* G1 = G0 + (size_t)64 * HDIM;
  const float* U0 = G0 + (size_t)IDIM * HDIM;
  const float* U1 = G1 + (size_t)IDIM * HDIM;
  // swizzled LDS write slots (write-side XOR == read-side XOR; no gll on this path)
  const int i0 = (r0 << 3) | (s ^ (r0 & 7));
  const int i1 = ((r0 + 64) << 3) | (s ^ (r0 & 7));   // (r0+64)&7 == r0&7

  float4 v[12];
  auto LOADS = [&](int k0) {   // 12 independent 16B loads
    v[0]  = *(const float4*)(A0 + k0); v[1]  = *(const float4*)(A0 + k0 + 4);
    v[2]  = *(const float4*)(A1 + k0); v[3]  = *(const float4*)(A1 + k0 + 4);
    v[4]  = *(const float4*)(G0 + k0); v[5]  = *(const float4*)(G0 + k0 + 4);
    v[6]  = *(const float4*)(G1 + k0); v[7]  = *(const float4*)(G1 + k0 + 4);
    v[8]  = *(const float4*)(U0 + k0); v[9]  = *(const float4*)(U0 + k0 + 4);
    v[10] = *(const float4*)(U1 + k0); v[11] = *(const float4*)(U1 + k0 + 4);
  };
  auto CVTWRITE = [&](int b) {   // fp32 regs -> bf16 -> swizzled LDS
    lds[b][0][i0] = cvt8r(v[0], v[1]);   lds[b][0][i1] = cvt8r(v[2], v[3]);
    lds[b][1][i0] = cvt8r(v[4], v[5]);   lds[b][1][i1] = cvt8r(v[6], v[7]);
    lds[b][2][i0] = cvt8r(v[8], v[9]);   lds[b][2][i1] = cvt8r(v[10], v[11]);
  };

  LOADS(0);
  CVTWRITE(0);
  #pragma unroll 1
  for (int kt = 0; kt < 16; ++kt) {            // NT = HDIM/64 = 16
    __syncthreads();                            // slot kt&1 visible; all waves past MFMA kt-1
    if (kt < 15) LOADS((kt + 1) * 64);          // issue early: latency hides under MFMA
    __builtin_amdgcn_sched_barrier(0);          // keep loads above the MFMA cluster
    const int cur = kt & 1;
    #pragma unroll
    for (int ks = 0; ks < 2; ++ks) {
      bf16x8 af[4], bgf[2], buf_[2];
      int slot = ks * 4 + (lane >> 4);
      #pragma unroll
      for (int i = 0; i < 4; ++i) {
        int row = wm * 64 + i * 16 + (lane & 15);
        af[i] = asbf(lds[cur][0][(row << 3) | (slot ^ (row & 7))]);
      }
      #pragma unroll
      for (int j = 0; j < 2; ++j) {
        int row = wn * 32 + j * 16 + (lane & 15);
        int idx = (row << 3) | (slot ^ (row & 7));
        bgf[j]  = asbf(lds[cur][1][idx]);
        buf_[j] = asbf(lds[cur][2][idx]);
      }
      #pragma unroll
      for (int i = 0; i < 4; ++i)
        #pragma unroll
        for (int j = 0; j < 2; ++j) {
          accg[i][j] = __builtin_amdgcn_mfma_f32_16x16x32_bf16(af[i], bgf[j],  accg[i][j], 0, 0, 0);
          accu[i][j] = __builtin_amdgcn_mfma_f32_16x16x32_bf16(af[i], buf_[j], accu[i][j], 0, 0, 0);
        }
    }
    if (kt < 15) CVTWRITE((kt + 1) & 1);        // write next slot; readers passed barrier
  }

  // epilogue: silu(g)*u*route_w -> bf16 h.
  // row < nrows guard REQUIRED: rows past nrows belong to the NEXT expert's tile.
  int fq = lane >> 4, fr = lane & 15;
  #pragma unroll
  for (int i = 0; i < 4; ++i)
    #pragma unroll
    for (int r = 0; r < 4; ++r) {
      int row = wm * 64 + i * 16 + fq * 4 + r;
      if (row < nrows) {
        float wgt = slot_w[mbase + row];
        #pragma unroll
        for (int j = 0; j < 2; ++j) {
          float g = accg[i][j][r], u = accu[i][j][r];
          float sg = g / (1.0f + __expf(-g));
          hbuf[(size_t)(mbase + row) * IDIM + n0 + wn * 32 + j * 16 + fr] = f2bf(sg * u * wgt);
        }
      }
    }
}

// ---------------- GEMM2 (fused cvt for W): out[tok] += h @ Wd^T ----------------
// 128x128 tiles, 512 threads, 2-slot LDS (64 KB -> 2 blocks/CU).
// A (hbuf, bf16) via global_load_lds w/ pre-swizzled source; B (down, fp32) reg-staged.
// grid 320 = 40 tiles x 8 n-stripes, XCD-chunked.
__global__ __launch_bounds__(512, 2) void gemm2_k(
    const u16* __restrict__ hbuf, const float* __restrict__ down,
    const Meta* __restrict__ meta, const int* __restrict__ slot_token,
    float* __restrict__ out) {
  int bid = blockIdx.x;
  int wg = (bid & 7) * 40 + (bid >> 3);   // 320/8 = 40 per XCD
  int tile = wg / 8, y = wg % 8;
  if (tile >= meta->n_tiles) return;
  int e = meta->tile_e[tile], mbase = meta->tile_m[tile], nrows = meta->tile_n[tile];
  int n0 = y * 128;

  __shared__ int4 lds[2][2][1024];   // [slot][A|B], 128x64 bf16 each; 64 KB
  int tid = threadIdx.x, lane = tid & 63, w = tid >> 6;
  int wm = w >> 2, wn = w & 3;
  f32x4 acc[4][2] = {};

  // A staging (bf16 gll): linear LDS dest + pre-swizzled global source (rule 21)
  int c0 = tid, c1 = tid + 512;
  int rA0 = c0 >> 3, sA0 = (c0 & 7) ^ (rA0 & 7);
  int rA1 = c1 >> 3, sA1 = (c1 & 7) ^ (rA1 & 7);
  const u16* a0 = hbuf + (size_t)(mbase + rA0) * IDIM + sA0 * 8;
  const u16* a1 = hbuf + (size_t)(mbase + rA1) * IDIM + sA1 * 8;

  // B staging (fp32 reg -> bf16 -> swizzled ds_write)
  int r0 = tid >> 3, s = tid & 7;
  const float* B0 = down + (size_t)e * HDIM * IDIM + (size_t)(n0 + r0) * IDIM + s * 8;
  const float* B1 = B0 + (size_t)64 * IDIM;
  const int i0 = (r0 << 3) | (s ^ (r0 & 7));
  const int i1 = ((r0 + 64) << 3) | (s ^ (r0 & 7));

  float4 vb[4];
  auto LOADS = [&](int b, int k0) {
    gll(a0 + k0, &lds[b][0][w * 64]);
    gll(a1 + k0, &lds[b][0][512 + w * 64]);
    vb[0] = *(const float4*)(B0 + k0); vb[1] = *(const float4*)(B0 + k0 + 4);
    vb[2] = *(const float4*)(B1 + k0); vb[3] = *(const float4*)(B1 + k0 + 4);
  };
  auto CVTWRITE = [&](int b) {
    lds[b][1][i0] = cvt8r(vb[0], vb[1]);
    lds[b][1][i1] = cvt8r(vb[2], vb[3]);
  };

  LOADS(0, 0);
  CVTWRITE(0);
  #pragma unroll 1
  for (int kt = 0; kt < 12; ++kt) {            // NT = IDIM/64 = 12
    __syncthreads();                            // drains vmcnt: slot kt&1 gll complete+visible
    if (kt < 11) LOADS((kt + 1) & 1, (kt + 1) * 64);
    __builtin_amdgcn_sched_barrier(0);
    const int cur = kt & 1;
    #pragma unroll
    for (int ks = 0; ks < 2; ++ks) {
      bf16x8 af[4], bf[2];
      int slot = ks * 4 + (lane >> 4);
      #pragma unroll
      for (int i = 0; i < 4; ++i) {
        int row = wm * 64 + i * 16 + (lane & 15);
        af[i] = asbf(lds[cur][0][(row << 3) | (slot ^ (row & 7))]);
      }
      #pragma unroll
      for (int j = 0; j < 2; ++j) {
        int row = wn * 32 + j * 16 + (lane & 15);
        bf[j] = asbf(lds[cur][1][(row << 3) | (slot ^ (row & 7))]);
      }
      #pragma unroll
      for (int i = 0; i < 4; ++i)
        #pragma unroll
        for (int j = 0; j < 2; ++j)
          acc[i][j] = __builtin_amdgcn_mfma_f32_16x16x32_bf16(af[i], bf[j], acc[i][j], 0, 0, 0);
    }
    if (kt < 11) CVTWRITE((kt + 1) & 1);
  }

  int fq = lane >> 4, fr = lane & 15;
  #pragma unroll
  for (int i = 0; i < 4; ++i)
    #pragma unroll
    for (int r = 0; r < 4; ++r) {
      int row = wm * 64 + i * 16 + fq * 4 + r;
      if (row < nrows) {
        int tok = slot_token[mbase + row];
        #pragma unroll
        for (int j = 0; j < 2; ++j)
          atomicAdd(out + (size_t)tok * HDIM + n0 + wn * 32 + j * 16 + fr, acc[i][j][r]);
      }
    }
}

extern "C" void kernel_launch(void* const* d_in, const int* in_sizes, int n_in,
                              void* d_out, int out_size, void* d_ws, size_t ws_size,
                              hipStream_t stream) {
  const float* hs   = (const float*)d_in[0];
  const float* gup  = (const float*)d_in[1];
  const float* down = (const float*)d_in[2];
  const int*   topk = (const int*)d_in[3];
  const float* tw   = (const float*)d_in[4];
  float* out = (float*)d_out;

  // workspace: meta + slot arrays + hbuf only (~8 MB)
  char* ws = (char*)d_ws;
  Meta*  meta       = (Meta*)ws;
  int*   slot_token = (int*)(ws + 4096);     // 5120*4
  float* slot_w     = (float*)(ws + 24576);  // 5120*4
  u16*   hbuf       = (u16*)(ws + 65536);    // 5120*768*2 = 7,864,320
  const size_t needed = 65536 + (size_t)SLOT_PAD * IDIM * 2;
  if (ws_size < needed) return;

  prep_k<<<257, 256, 0, stream>>>(topk, tw, meta, slot_token, slot_w, out);
  gemm1_k<<<MAX_TILES * 6, 512, 0, stream>>>(hs, gup, meta, slot_token, slot_w, hbuf);
  gemm2_k<<<MAX_TILES * 8, 512, 0, stream>>>(hbuf, down, meta, slot_token, out);
}

// Round 10
// 177.817 us; speedup vs baseline: 1.1155x; 1.1155x over previous
//
#include <hip/hip_runtime.h>
#include <hip/hip_bf16.h>

#define T_TOK   2048
#define NEXP    8
#define HDIM    1024
#define IDIM    768
#define TOPK    2
#define NASSIGN (T_TOK*TOPK)
#define MT      128
#define MAX_TILES 40
#define SLOT_PAD 5120   // MAX_TILES*128

typedef unsigned short u16;
typedef unsigned int   u32;

typedef __bf16 bf16x8 __attribute__((ext_vector_type(8)));
typedef float  f32x4  __attribute__((ext_vector_type(4)));

struct Meta {
  int n_tiles;
  int _pad[15];
  int tile_e[80];
  int tile_m[80];
  int tile_n[80];
};

__device__ __forceinline__ u16 f2bf(float f) {
  u32 x = __float_as_uint(f);
  return (u16)((x + 0x7fffu + ((x >> 16) & 1u)) >> 16);   // RNE, inputs finite
}

// pack two float4 (8 consecutive fp32) -> int4 of 8 bf16
__device__ __forceinline__ int4 cvt8r(float4 a, float4 b) {
  union { u16 u[8]; int4 v; } r;
  r.u[0] = f2bf(a.x); r.u[1] = f2bf(a.y); r.u[2] = f2bf(a.z); r.u[3] = f2bf(a.w);
  r.u[4] = f2bf(b.x); r.u[5] = f2bf(b.y); r.u[6] = f2bf(b.z); r.u[7] = f2bf(b.w);
  return r.v;
}

__device__ __forceinline__ bf16x8 asbf(int4 v) {
  return __builtin_bit_cast(bf16x8, v);
}

// async global->LDS, 16B per lane; lds ptr wave-uniform (lane scatters +16B each)
__device__ __forceinline__ void gll(const void* g, void* l) {
  __builtin_amdgcn_global_load_lds(
      (const __attribute__((address_space(1))) u32*)g,
      (__attribute__((address_space(3))) u32*)l, 16, 0, 0);
}

// ---------------- prep: route (block 0) + fp32->bf16 converts + zero d_out ----------------
// Convert blocks use explicit two-phase batches: ALL loads into named regs first,
// then all cvt+stores -> ~12 loads in flight/thread (r8's pack8-inline kept only ~2,
// measured 3.1 cyc/VMEM-inst vs fill's 1.5 -> latency-chain bound, not BW/issue).
__global__ __launch_bounds__(256, 4) void prep_k(
    const float* __restrict__ hs, const float* __restrict__ gup,
    const float* __restrict__ down, const int* __restrict__ topk,
    const float* __restrict__ tw,
    u16* __restrict__ hs16, u16* __restrict__ gup16, u16* __restrict__ down16,
    Meta* __restrict__ meta, int* __restrict__ slot_token, float* __restrict__ slot_w,
    float* __restrict__ out) {
  int tid = threadIdx.x;

  if (blockIdx.x == 0) {   // routing only
    __shared__ int s_cnt[NEXP], s_off[NEXP], s_cur[NEXP];
    if (tid < NEXP) { s_cnt[tid] = 0; s_cur[tid] = 0; }
    __syncthreads();
    for (int i = tid; i < NASSIGN; i += 256)
      atomicAdd(&s_cnt[topk[i]], 1);
    __syncthreads();
    if (tid == 0) {
      int acc = 0, nt = 0;
      for (int e = 0; e < NEXP; ++e) {
        s_off[e] = acc;
        int c = s_cnt[e];
        for (int mb = 0; mb < c; mb += MT) {
          meta->tile_e[nt] = e;
          meta->tile_m[nt] = acc + mb;
          meta->tile_n[nt] = (c - mb) < MT ? (c - mb) : MT;
          ++nt;
        }
        acc += c;
      }
      meta->n_tiles = nt;
    }
    __syncthreads();
    for (int i = tid; i < NASSIGN; i += 256) {
      int e = topk[i];
      int p = s_off[e] + atomicAdd(&s_cur[e], 1);
      slot_token[p] = i / TOPK;
      slot_w[p]     = tw[i];
    }
    for (int i = NASSIGN + tid; i < SLOT_PAD; i += 256) {  // pad: token 0, weight 0
      slot_token[i] = 0;
      slot_w[i]     = 0.0f;
    }
    return;
  }

  const size_t NTH = 1024 * 256;                 // 262,144 conversion threads
  size_t t = ((size_t)blockIdx.x - 1) * 256 + tid;

  // gup: 1,572,864 groups = 6/thread. Phase A: 12 loads; Phase B: 6 cvt+stores.
  {
    float4 v[12];
    #pragma unroll
    for (int k = 0; k < 6; ++k) {
      size_t i = t + (size_t)k * NTH;
      v[2*k]   = *(const float4*)(gup + i * 8);
      v[2*k+1] = *(const float4*)(gup + i * 8 + 4);
    }
    #pragma unroll
    for (int k = 0; k < 6; ++k) {
      size_t i = t + (size_t)k * NTH;
      *(int4*)(gup16 + i * 8) = cvt8r(v[2*k], v[2*k+1]);
    }
  }
  // down: 786,432 groups = 3/thread
  {
    float4 v[6];
    #pragma unroll
    for (int k = 0; k < 3; ++k) {
      size_t i = t + (size_t)k * NTH;
      v[2*k]   = *(const float4*)(down + i * 8);
      v[2*k+1] = *(const float4*)(down + i * 8 + 4);
    }
    #pragma unroll
    for (int k = 0; k < 3; ++k) {
      size_t i = t + (size_t)k * NTH;
      *(int4*)(down16 + i * 8) = cvt8r(v[2*k], v[2*k+1]);
    }
  }
  // hs: 262,144 groups = 1/thread
  {
    float4 a = *(const float4*)(hs + t * 8);
    float4 b = *(const float4*)(hs + t * 8 + 4);
    *(int4*)(hs16 + t * 8) = cvt8r(a, b);
  }
  // zero d_out: 524,288 int4 = 2/thread
  int4 z = {0, 0, 0, 0};
  *(int4*)(out + t * 4) = z;
  *(int4*)(out + (t + NTH) * 4) = z;
}

// ---------------- GEMM1: h = silu(x@Wg^T) * (x@Wu^T) * route_w ----------------
// 128x128 tiles, 512 threads (2x4 waves), 3-slot LDS (144 KB), counted vmcnt.
// grid 240 = 40 tiles x 6 n-stripes, XCD-chunked.
__global__ __launch_bounds__(512, 2) void gemm1_k(
    const u16* __restrict__ hs16, const u16* __restrict__ gup16,
    const Meta* __restrict__ meta, const int* __restrict__ slot_token,
    const float* __restrict__ slot_w, u16* __restrict__ hbuf) {
  int bid = blockIdx.x;
  int wg = (bid & 7) * 30 + (bid >> 3);   // 240/8 = 30 per XCD: ~5 tiles ~ 1 expert
  int tile = wg / 6, y = wg % 6;
  if (tile >= meta->n_tiles) return;
  int e = meta->tile_e[tile], mbase = meta->tile_m[tile], nrows = meta->tile_n[tile];
  int n0 = y * 128;

  __shared__ int4 lds[3][3][1024];   // [slot][A|Bg|Bu], 128x64 bf16 each; 144 KB
  int tid = threadIdx.x, lane = tid & 63, w = tid >> 6;
  int wm = w >> 2, wn = w & 3;       // wave grid 2(M) x 4(N); wave tile 64x32
  f32x4 accg[4][2] = {}, accu[4][2] = {};

  const u16* gb = gup16 + (size_t)e * (2 * IDIM) * HDIM + (size_t)n0 * HDIM;
  const u16* ub = gb + (size_t)IDIM * HDIM;

  // per-thread staging coords; source pre-swizzled (slot ^ row&7), LDS linear (rule 21)
  int c0 = tid, c1 = tid + 512;
  int r0 = c0 >> 3, s0 = (c0 & 7) ^ (r0 & 7);
  int r1 = c1 >> 3, s1 = (c1 & 7) ^ (r1 & 7);
  const u16* a0 = hs16 + (size_t)slot_token[mbase + r0] * HDIM + s0 * 8;
  const u16* a1 = hs16 + (size_t)slot_token[mbase + r1] * HDIM + s1 * 8;
  const u16* g0 = gb + (size_t)r0 * HDIM + s0 * 8;
  const u16* g1 = gb + (size_t)r1 * HDIM + s1 * 8;
  const u16* u0 = ub + (size_t)r0 * HDIM + s0 * 8;
  const u16* u1 = ub + (size_t)r1 * HDIM + s1 * 8;

  auto STAGE = [&](int b, int k0) {   // 6 gll per wave
    gll(a0 + k0, &lds[b][0][w * 64]);
    gll(a1 + k0, &lds[b][0][512 + w * 64]);
    gll(g0 + k0, &lds[b][1][w * 64]);
    gll(g1 + k0, &lds[b][1][512 + w * 64]);
    gll(u0 + k0, &lds[b][2][w * 64]);
    gll(u1 + k0, &lds[b][2][512 + w * 64]);
  };

  STAGE(0, 0);
  STAGE(1, 64);
  #pragma unroll
  for (int kt = 0; kt < 16; ++kt) {          // NT = HDIM/64 = 16
    __builtin_amdgcn_s_barrier();            // iter kt-1 readers done with slot (kt+2)%3
    if (kt + 2 < 16) STAGE((kt + 2) % 3, (kt + 2) * 64);
    if (kt < 14)       asm volatile("s_waitcnt vmcnt(12)" ::: "memory");
    else if (kt == 14) asm volatile("s_waitcnt vmcnt(6)" ::: "memory");
    else               asm volatile("s_waitcnt vmcnt(0)" ::: "memory");
    __builtin_amdgcn_sched_barrier(0);
    const int cur = kt % 3;
    #pragma unroll
    for (int ks = 0; ks < 2; ++ks) {
      bf16x8 af[4], bgf[2], buf_[2];
      int slot = ks * 4 + (lane >> 4);
      #pragma unroll
      for (int i = 0; i < 4; ++i) {
        int row = wm * 64 + i * 16 + (lane & 15);
        af[i] = asbf(lds[cur][0][(row << 3) | (slot ^ (row & 7))]);
      }
      #pragma unroll
      for (int j = 0; j < 2; ++j) {
        int row = wn * 32 + j * 16 + (lane & 15);
        int idx = (row << 3) | (slot ^ (row & 7));
        bgf[j]  = asbf(lds[cur][1][idx]);
        buf_[j] = asbf(lds[cur][2][idx]);
      }
      #pragma unroll
      for (int i = 0; i < 4; ++i)
        #pragma unroll
        for (int j = 0; j < 2; ++j) {
          accg[i][j] = __builtin_amdgcn_mfma_f32_16x16x32_bf16(af[i], bgf[j],  accg[i][j], 0, 0, 0);
          accu[i][j] = __builtin_amdgcn_mfma_f32_16x16x32_bf16(af[i], buf_[j], accu[i][j], 0, 0, 0);
        }
    }
  }

  // epilogue: silu(g)*u*route_w -> bf16 h.
  // row < nrows guard REQUIRED: rows past nrows belong to the NEXT expert's tile.
  int fq = lane >> 4, fr = lane & 15;
  #pragma unroll
  for (int i = 0; i < 4; ++i)
    #pragma unroll
    for (int r = 0; r < 4; ++r) {
      int row = wm * 64 + i * 16 + fq * 4 + r;
      if (row < nrows) {
        float wgt = slot_w[mbase + row];
        #pragma unroll
        for (int j = 0; j < 2; ++j) {
          float g = accg[i][j][r], u = accu[i][j][r];
          float s = g / (1.0f + __expf(-g));
          hbuf[(size_t)(mbase + row) * IDIM + n0 + wn * 32 + j * 16 + fr] = f2bf(s * u * wgt);
        }
      }
    }
}

// ---------------- GEMM2: out[tok] += h @ Wd^T ----------------
// 128x128 tiles, 512 threads, 2-slot LDS (64 KB -> 2 blocks/CU), counted vmcnt.
// grid 320 = 40 tiles x 8 n-stripes, XCD-chunked.
__global__ __launch_bounds__(512, 4) void gemm2_k(
    const u16* __restrict__ hbuf, const u16* __restrict__ down16,
    const Meta* __restrict__ meta, const int* __restrict__ slot_token,
    float* __restrict__ out) {
  int bid = blockIdx.x;
  int wg = (bid & 7) * 40 + (bid >> 3);   // 320/8 = 40 per XCD
  int tile = wg / 8, y = wg % 8;
  if (tile >= meta->n_tiles) return;
  int e = meta->tile_e[tile], mbase = meta->tile_m[tile], nrows = meta->tile_n[tile];
  int n0 = y * 128;

  __shared__ int4 lds[2][2][1024];   // [slot][A|B], 128x64 bf16 each; 64 KB
  int tid = threadIdx.x, lane = tid & 63, w = tid >> 6;
  int wm = w >> 2, wn = w & 3;
  f32x4 acc[4][2] = {};
  const u16* db = down16 + (size_t)e * HDIM * IDIM + (size_t)n0 * IDIM;

  int c0 = tid, c1 = tid + 512;
  int r0 = c0 >> 3, s0 = (c0 & 7) ^ (r0 & 7);
  int r1 = c1 >> 3, s1 = (c1 & 7) ^ (r1 & 7);
  const u16* a0 = hbuf + (size_t)(mbase + r0) * IDIM + s0 * 8;
  const u16* a1 = hbuf + (size_t)(mbase + r1) * IDIM + s1 * 8;
  const u16* b0 = db + (size_t)r0 * IDIM + s0 * 8;
  const u16* b1 = db + (size_t)r1 * IDIM + s1 * 8;

  auto STAGE = [&](int b, int k0) {   // 4 gll per wave
    gll(a0 + k0, &lds[b][0][w * 64]);
    gll(a1 + k0, &lds[b][0][512 + w * 64]);
    gll(b0 + k0, &lds[b][1][w * 64]);
    gll(b1 + k0, &lds[b][1][512 + w * 64]);
  };

  STAGE(0, 0);
  #pragma unroll
  for (int kt = 0; kt < 12; ++kt) {          // NT = IDIM/64 = 12
    __builtin_amdgcn_s_barrier();            // iter kt-1 readers done with slot (kt+1)&1
    if (kt + 1 < 12) STAGE((kt + 1) & 1, (kt + 1) * 64);
    if (kt < 11) asm volatile("s_waitcnt vmcnt(4)" ::: "memory");
    else         asm volatile("s_waitcnt vmcnt(0)" ::: "memory");
    __builtin_amdgcn_sched_barrier(0);
    const int cur = kt & 1;
    #pragma unroll
    for (int ks = 0; ks < 2; ++ks) {
      bf16x8 af[4], bf[2];
      int slot = ks * 4 + (lane >> 4);
      #pragma unroll
      for (int i = 0; i < 4; ++i) {
        int row = wm * 64 + i * 16 + (lane & 15);
        af[i] = asbf(lds[cur][0][(row << 3) | (slot ^ (row & 7))]);
      }
      #pragma unroll
      for (int j = 0; j < 2; ++j) {
        int row = wn * 32 + j * 16 + (lane & 15);
        bf[j] = asbf(lds[cur][1][(row << 3) | (slot ^ (row & 7))]);
      }
      #pragma unroll
      for (int i = 0; i < 4; ++i)
        #pragma unroll
        for (int j = 0; j < 2; ++j)
          acc[i][j] = __builtin_amdgcn_mfma_f32_16x16x32_bf16(af[i], bf[j], acc[i][j], 0, 0, 0);
    }
  }

  int fq = lane >> 4, fr = lane & 15;
  #pragma unroll
  for (int i = 0; i < 4; ++i)
    #pragma unroll
    for (int r = 0; r < 4; ++r) {
      int row = wm * 64 + i * 16 + fq * 4 + r;
      if (row < nrows) {
        int tok = slot_token[mbase + row];
        #pragma unroll
        for (int j = 0; j < 2; ++j)
          atomicAdd(out + (size_t)tok * HDIM + n0 + wn * 32 + j * 16 + fr, acc[i][j][r]);
      }
    }
}

extern "C" void kernel_launch(void* const* d_in, const int* in_sizes, int n_in,
                              void* d_out, int out_size, void* d_ws, size_t ws_size,
                              hipStream_t stream) {
  const float* hs   = (const float*)d_in[0];
  const float* gup  = (const float*)d_in[1];
  const float* down = (const float*)d_in[2];
  const int*   topk = (const int*)d_in[3];
  const float* tw   = (const float*)d_in[4];
  float* out = (float*)d_out;

  // workspace layout (16B-aligned)
  const size_t o_hs16   = 65536;
  const size_t o_hbuf   = o_hs16 + (size_t)T_TOK * HDIM * 2;               //  4,259,840
  const size_t o_gup16  = o_hbuf + (size_t)SLOT_PAD * IDIM * 2;            // 12,124,160
  const size_t o_down16 = o_gup16 + (size_t)NEXP * 2 * IDIM * HDIM * 2;    // 37,289,984
  const size_t needed   = o_down16 + (size_t)NEXP * HDIM * IDIM * 2;       // 49,872,896

  char* ws = (char*)d_ws;
  Meta*  meta       = (Meta*)ws;
  int*   slot_token = (int*)(ws + 4096);     // 5120*4 -> ends 24,576
  float* slot_w     = (float*)(ws + 24576);  // 5120*4 -> ends 45,056
  u16*   hs16       = (u16*)(ws + o_hs16);
  u16*   hbuf       = (u16*)(ws + o_hbuf);
  u16*   gup16      = (u16*)(ws + o_gup16);
  u16*   down16     = (u16*)(ws + o_down16);

  if (ws_size < needed) return;

  prep_k<<<1025, 256, 0, stream>>>(hs, gup, down, topk, tw,
                                   hs16, gup16, down16, meta, slot_token, slot_w, out);
  gemm1_k<<<MAX_TILES * 6, 512, 0, stream>>>(hs16, gup16, meta, slot_token, slot_w, hbuf);
  gemm2_k<<<MAX_TILES * 8, 512, 0, stream>>>(hbuf, down16, meta, slot_token, out);
}

// Round 12
// 176.396 us; speedup vs baseline: 1.1245x; 1.0081x over previous
//
#include <hip/hip_runtime.h>
#include <hip/hip_bf16.h>

#define T_TOK   2048
#define NEXP    8
#define HDIM    1024
#define IDIM    768
#define TOPK    2
#define NASSIGN (T_TOK*TOPK)
#define MT      128
#define MAX_TILES 40
#define SLOT_PAD 5120   // MAX_TILES*128

typedef unsigned short u16;
typedef unsigned int   u32;

typedef __bf16 bf16x8 __attribute__((ext_vector_type(8)));
typedef float  f32x4  __attribute__((ext_vector_type(4)));

struct Meta {
  int n_tiles;
  int _pad[15];
  int tile_e[80];
  int tile_m[80];
  int tile_n[80];
};

__device__ __forceinline__ u16 f2bf(float f) {
  u32 x = __float_as_uint(f);
  return (u16)((x + 0x7fffu + ((x >> 16) & 1u)) >> 16);   // RNE, inputs finite
}

// pack two float4 (8 consecutive fp32) -> int4 of 8 bf16
__device__ __forceinline__ int4 cvt8r(float4 a, float4 b) {
  union { u16 u[8]; int4 v; } r;
  r.u[0] = f2bf(a.x); r.u[1] = f2bf(a.y); r.u[2] = f2bf(a.z); r.u[3] = f2bf(a.w);
  r.u[4] = f2bf(b.x); r.u[5] = f2bf(b.y); r.u[6] = f2bf(b.z); r.u[7] = f2bf(b.w);
  return r.v;
}

__device__ __forceinline__ bf16x8 asbf(int4 v) {
  return __builtin_bit_cast(bf16x8, v);
}

// async global->LDS, 16B per lane; lds ptr wave-uniform (lane scatters +16B each)
__device__ __forceinline__ void gll(const void* g, void* l) {
  __builtin_amdgcn_global_load_lds(
      (const __attribute__((address_space(1))) u32*)g,
      (__attribute__((address_space(3))) u32*)l, 16, 0, 0);
}

// ---------------- prep: route (block 0) + fp32->bf16 converts + zero d_out ----------------
// ALL 20 float4 loads issued, then sched_barrier(0) -- the scheduler cannot re-fuse
// load->cvt chains across it (r10 failure mode: VGPR stayed 32, loads were sunk).
// Expected VGPR ~100; expected prep ~22-27 us (BW floor 137 MB @ ~6.5 TB/s = 21).
__global__ __launch_bounds__(256, 4) void prep_k(
    const float* __restrict__ hs, const float* __restrict__ gup,
    const float* __restrict__ down, const int* __restrict__ topk,
    const float* __restrict__ tw,
    u16* __restrict__ hs16, u16* __restrict__ gup16, u16* __restrict__ down16,
    Meta* __restrict__ meta, int* __restrict__ slot_token, float* __restrict__ slot_w,
    float* __restrict__ out) {
  int tid = threadIdx.x;

  if (blockIdx.x == 0) {   // routing only
    __shared__ int s_cnt[NEXP], s_off[NEXP], s_cur[NEXP];
    if (tid < NEXP) { s_cnt[tid] = 0; s_cur[tid] = 0; }
    __syncthreads();
    for (int i = tid; i < NASSIGN; i += 256)
      atomicAdd(&s_cnt[topk[i]], 1);
    __syncthreads();
    if (tid == 0) {
      int acc = 0, nt = 0;
      for (int e = 0; e < NEXP; ++e) {
        s_off[e] = acc;
        int c = s_cnt[e];
        for (int mb = 0; mb < c; mb += MT) {
          meta->tile_e[nt] = e;
          meta->tile_m[nt] = acc + mb;
          meta->tile_n[nt] = (c - mb) < MT ? (c - mb) : MT;
          ++nt;
        }
        acc += c;
      }
      meta->n_tiles = nt;
    }
    __syncthreads();
    for (int i = tid; i < NASSIGN; i += 256) {
      int e = topk[i];
      int p = s_off[e] + atomicAdd(&s_cur[e], 1);
      slot_token[p] = i / TOPK;
      slot_w[p]     = tw[i];
    }
    for (int i = NASSIGN + tid; i < SLOT_PAD; i += 256) {  // pad: token 0, weight 0
      slot_token[i] = 0;
      slot_w[i]     = 0.0f;
    }
    return;
  }

  const size_t NTH = 1024 * 256;                 // 262,144 conversion threads
  size_t t = ((size_t)blockIdx.x - 1) * 256 + tid;

  // zero d_out first (independent stores, no waits): 524,288 int4 = 2/thread
  int4 z = {0, 0, 0, 0};
  *(int4*)(out + t * 4) = z;
  *(int4*)(out + (t + NTH) * 4) = z;

  // ---- phase A: issue ALL loads (gup 12, down 6, hs 2 = 20 float4 = 80 VGPR) ----
  float4 vg0a = *(const float4*)(gup + (t + 0 * NTH) * 8);
  float4 vg0b = *(const float4*)(gup + (t + 0 * NTH) * 8 + 4);
  float4 vg1a = *(const float4*)(gup + (t + 1 * NTH) * 8);
  float4 vg1b = *(const float4*)(gup + (t + 1 * NTH) * 8 + 4);
  float4 vg2a = *(const float4*)(gup + (t + 2 * NTH) * 8);
  float4 vg2b = *(const float4*)(gup + (t + 2 * NTH) * 8 + 4);
  float4 vg3a = *(const float4*)(gup + (t + 3 * NTH) * 8);
  float4 vg3b = *(const float4*)(gup + (t + 3 * NTH) * 8 + 4);
  float4 vg4a = *(const float4*)(gup + (t + 4 * NTH) * 8);
  float4 vg4b = *(const float4*)(gup + (t + 4 * NTH) * 8 + 4);
  float4 vg5a = *(const float4*)(gup + (t + 5 * NTH) * 8);
  float4 vg5b = *(const float4*)(gup + (t + 5 * NTH) * 8 + 4);
  float4 vd0a = *(const float4*)(down + (t + 0 * NTH) * 8);
  float4 vd0b = *(const float4*)(down + (t + 0 * NTH) * 8 + 4);
  float4 vd1a = *(const float4*)(down + (t + 1 * NTH) * 8);
  float4 vd1b = *(const float4*)(down + (t + 1 * NTH) * 8 + 4);
  float4 vd2a = *(const float4*)(down + (t + 2 * NTH) * 8);
  float4 vd2b = *(const float4*)(down + (t + 2 * NTH) * 8 + 4);
  float4 vh0a = *(const float4*)(hs + t * 8);
  float4 vh0b = *(const float4*)(hs + t * 8 + 4);

  __builtin_amdgcn_sched_barrier(0);   // nothing crosses: loads stay batched above

  // ---- phase B: convert + store ----
  *(int4*)(gup16 + (t + 0 * NTH) * 8) = cvt8r(vg0a, vg0b);
  *(int4*)(gup16 + (t + 1 * NTH) * 8) = cvt8r(vg1a, vg1b);
  *(int4*)(gup16 + (t + 2 * NTH) * 8) = cvt8r(vg2a, vg2b);
  *(int4*)(gup16 + (t + 3 * NTH) * 8) = cvt8r(vg3a, vg3b);
  *(int4*)(gup16 + (t + 4 * NTH) * 8) = cvt8r(vg4a, vg4b);
  *(int4*)(gup16 + (t + 5 * NTH) * 8) = cvt8r(vg5a, vg5b);
  *(int4*)(down16 + (t + 0 * NTH) * 8) = cvt8r(vd0a, vd0b);
  *(int4*)(down16 + (t + 1 * NTH) * 8) = cvt8r(vd1a, vd1b);
  *(int4*)(down16 + (t + 2 * NTH) * 8) = cvt8r(vd2a, vd2b);
  *(int4*)(hs16 + t * 8) = cvt8r(vh0a, vh0b);
}

// ---------------- GEMM1: h = silu(x@Wg^T) * (x@Wu^T) * route_w ----------------
// 128x128 tiles, 512 threads (2x4 waves), 3-slot LDS (144 KB), counted vmcnt.
// grid 240 = 40 tiles x 6 n-stripes, XCD-chunked.
__global__ __launch_bounds__(512, 2) void gemm1_k(
    const u16* __restrict__ hs16, const u16* __restrict__ gup16,
    const Meta* __restrict__ meta, const int* __restrict__ slot_token,
    const float* __restrict__ slot_w, u16* __restrict__ hbuf) {
  int bid = blockIdx.x;
  int wg = (bid & 7) * 30 + (bid >> 3);   // 240/8 = 30 per XCD: ~5 tiles ~ 1 expert
  int tile = wg / 6, y = wg % 6;
  if (tile >= meta->n_tiles) return;
  int e = meta->tile_e[tile], mbase = meta->tile_m[tile], nrows = meta->tile_n[tile];
  int n0 = y * 128;

  __shared__ int4 lds[3][3][1024];   // [slot][A|Bg|Bu], 128x64 bf16 each; 144 KB
  int tid = threadIdx.x, lane = tid & 63, w = tid >> 6;
  int wm = w >> 2, wn = w & 3;       // wave grid 2(M) x 4(N); wave tile 64x32
  f32x4 accg[4][2] = {}, accu[4][2] = {};

  const u16* gb = gup16 + (size_t)e * (2 * IDIM) * HDIM + (size_t)n0 * HDIM;
  const u16* ub = gb + (size_t)IDIM * HDIM;

  // per-thread staging coords; source pre-swizzled (slot ^ row&7), LDS linear (rule 21)
  int c0 = tid, c1 = tid + 512;
  int r0 = c0 >> 3, s0 = (c0 & 7) ^ (r0 & 7);
  int r1 = c1 >> 3, s1 = (c1 & 7) ^ (r1 & 7);
  const u16* a0 = hs16 + (size_t)slot_token[mbase + r0] * HDIM + s0 * 8;
  const u16* a1 = hs16 + (size_t)slot_token[mbase + r1] * HDIM + s1 * 8;
  const u16* g0 = gb + (size_t)r0 * HDIM + s0 * 8;
  const u16* g1 = gb + (size_t)r1 * HDIM + s1 * 8;
  const u16* u0 = ub + (size_t)r0 * HDIM + s0 * 8;
  const u16* u1 = ub + (size_t)r1 * HDIM + s1 * 8;

  auto STAGE = [&](int b, int k0) {   // 6 gll per wave
    gll(a0 + k0, &lds[b][0][w * 64]);
    gll(a1 + k0, &lds[b][0][512 + w * 64]);
    gll(g0 + k0, &lds[b][1][w * 64]);
    gll(g1 + k0, &lds[b][1][512 + w * 64]);
    gll(u0 + k0, &lds[b][2][w * 64]);
    gll(u1 + k0, &lds[b][2][512 + w * 64]);
  };

  STAGE(0, 0);
  STAGE(1, 64);
  #pragma unroll
  for (int kt = 0; kt < 16; ++kt) {          // NT = HDIM/64 = 16
    __builtin_amdgcn_s_barrier();            // iter kt-1 readers done with slot (kt+2)%3
    if (kt + 2 < 16) STAGE((kt + 2) % 3, (kt + 2) * 64);
    if (kt < 14)       asm volatile("s_waitcnt vmcnt(12)" ::: "memory");
    else if (kt == 14) asm volatile("s_waitcnt vmcnt(6)" ::: "memory");
    else               asm volatile("s_waitcnt vmcnt(0)" ::: "memory");
    __builtin_amdgcn_sched_barrier(0);
    const int cur = kt % 3;
    #pragma unroll
    for (int ks = 0; ks < 2; ++ks) {
      bf16x8 af[4], bgf[2], buf_[2];
      int slot = ks * 4 + (lane >> 4);
      #pragma unroll
      for (int i = 0; i < 4; ++i) {
        int row = wm * 64 + i * 16 + (lane & 15);
        af[i] = asbf(lds[cur][0][(row << 3) | (slot ^ (row & 7))]);
      }
      #pragma unroll
      for (int j = 0; j < 2; ++j) {
        int row = wn * 32 + j * 16 + (lane & 15);
        int idx = (row << 3) | (slot ^ (row & 7));
        bgf[j]  = asbf(lds[cur][1][idx]);
        buf_[j] = asbf(lds[cur][2][idx]);
      }
      #pragma unroll
      for (int i = 0; i < 4; ++i)
        #pragma unroll
        for (int j = 0; j < 2; ++j) {
          accg[i][j] = __builtin_amdgcn_mfma_f32_16x16x32_bf16(af[i], bgf[j],  accg[i][j], 0, 0, 0);
          accu[i][j] = __builtin_amdgcn_mfma_f32_16x16x32_bf16(af[i], buf_[j], accu[i][j], 0, 0, 0);
        }
    }
  }

  // epilogue: silu(g)*u*route_w -> bf16 h.
  // row < nrows guard REQUIRED: rows past nrows belong to the NEXT expert's tile.
  int fq = lane >> 4, fr = lane & 15;
  #pragma unroll
  for (int i = 0; i < 4; ++i)
    #pragma unroll
    for (int r = 0; r < 4; ++r) {
      int row = wm * 64 + i * 16 + fq * 4 + r;
      if (row < nrows) {
        float wgt = slot_w[mbase + row];
        #pragma unroll
        for (int j = 0; j < 2; ++j) {
          float g = accg[i][j][r], u = accu[i][j][r];
          float s = g / (1.0f + __expf(-g));
          hbuf[(size_t)(mbase + row) * IDIM + n0 + wn * 32 + j * 16 + fr] = f2bf(s * u * wgt);
        }
      }
    }
}

// ---------------- GEMM2: out[tok] += h @ Wd^T ----------------
// 128x128 tiles, 512 threads, 2-slot LDS (64 KB -> 2 blocks/CU), counted vmcnt.
// grid 320 = 40 tiles x 8 n-stripes, XCD-chunked.
__global__ __launch_bounds__(512, 4) void gemm2_k(
    const u16* __restrict__ hbuf, const u16* __restrict__ down16,
    const Meta* __restrict__ meta, const int* __restrict__ slot_token,
    float* __restrict__ out) {
  int bid = blockIdx.x;
  int wg = (bid & 7) * 40 + (bid >> 3);   // 320/8 = 40 per XCD
  int tile = wg / 8, y = wg % 8;
  if (tile >= meta->n_tiles) return;
  int e = meta->tile_e[tile], mbase = meta->tile_m[tile], nrows = meta->tile_n[tile];
  int n0 = y * 128;

  __shared__ int4 lds[2][2][1024];   // [slot][A|B], 128x64 bf16 each; 64 KB
  int tid = threadIdx.x, lane = tid & 63, w = tid >> 6;
  int wm = w >> 2, wn = w & 3;
  f32x4 acc[4][2] = {};
  const u16* db = down16 + (size_t)e * HDIM * IDIM + (size_t)n0 * IDIM;

  int c0 = tid, c1 = tid + 512;
  int r0 = c0 >> 3, s0 = (c0 & 7) ^ (r0 & 7);
  int r1 = c1 >> 3, s1 = (c1 & 7) ^ (r1 & 7);
  const u16* a0 = hbuf + (size_t)(mbase + r0) * IDIM + s0 * 8;
  const u16* a1 = hbuf + (size_t)(mbase + r1) * IDIM + s1 * 8;
  const u16* b0 = db + (size_t)r0 * IDIM + s0 * 8;
  const u16* b1 = db + (size_t)r1 * IDIM + s1 * 8;

  auto STAGE = [&](int b, int k0) {   // 4 gll per wave
    gll(a0 + k0, &lds[b][0][w * 64]);
    gll(a1 + k0, &lds[b][0][512 + w * 64]);
    gll(b0 + k0, &lds[b][1][w * 64]);
    gll(b1 + k0, &lds[b][1][512 + w * 64]);
  };

  STAGE(0, 0);
  #pragma unroll
  for (int kt = 0; kt < 12; ++kt) {          // NT = IDIM/64 = 12
    __builtin_amdgcn_s_barrier();            // iter kt-1 readers done with slot (kt+1)&1
    if (kt + 1 < 12) STAGE((kt + 1) & 1, (kt + 1) * 64);
    if (kt < 11) asm volatile("s_waitcnt vmcnt(4)" ::: "memory");
    else         asm volatile("s_waitcnt vmcnt(0)" ::: "memory");
    __builtin_amdgcn_sched_barrier(0);
    const int cur = kt & 1;
    #pragma unroll
    for (int ks = 0; ks < 2; ++ks) {
      bf16x8 af[4], bf[2];
      int slot = ks * 4 + (lane >> 4);
      #pragma unroll
      for (int i = 0; i < 4; ++i) {
        int row = wm * 64 + i * 16 + (lane & 15);
        af[i] = asbf(lds[cur][0][(row << 3) | (slot ^ (row & 7))]);
      }
      #pragma unroll
      for (int j = 0; j < 2; ++j) {
        int row = wn * 32 + j * 16 + (lane & 15);
        bf[j] = asbf(lds[cur][1][(row << 3) | (slot ^ (row & 7))]);
      }
      #pragma unroll
      for (int i = 0; i < 4; ++i)
        #pragma unroll
        for (int j = 0; j < 2; ++j)
          acc[i][j] = __builtin_amdgcn_mfma_f32_16x16x32_bf16(af[i], bf[j], acc[i][j], 0, 0, 0);
    }
  }

  int fq = lane >> 4, fr = lane & 15;
  #pragma unroll
  for (int i = 0; i < 4; ++i)
    #pragma unroll
    for (int r = 0; r < 4; ++r) {
      int row = wm * 64 + i * 16 + fq * 4 + r;
      if (row < nrows) {
        int tok = slot_token[mbase + row];
        #pragma unroll
        for (int j = 0; j < 2; ++j)
          atomicAdd(out + (size_t)tok * HDIM + n0 + wn * 32 + j * 16 + fr, acc[i][j][r]);
      }
    }
}

extern "C" void kernel_launch(void* const* d_in, const int* in_sizes, int n_in,
                              void* d_out, int out_size, void* d_ws, size_t ws_size,
                              hipStream_t stream) {
  const float* hs   = (const float*)d_in[0];
  const float* gup  = (const float*)d_in[1];
  const float* down = (const float*)d_in[2];
  const int*   topk = (const int*)d_in[3];
  const float* tw   = (const float*)d_in[4];
  float* out = (float*)d_out;

  // workspace layout (16B-aligned)
  const size_t o_hs16   = 65536;
  const size_t o_hbuf   = o_hs16 + (size_t)T_TOK * HDIM * 2;               //  4,259,840
  const size_t o_gup16  = o_hbuf + (size_t)SLOT_PAD * IDIM * 2;            // 12,124,160
  const size_t o_down16 = o_gup16 + (size_t)NEXP * 2 * IDIM * HDIM * 2;    // 37,289,984
  const size_t needed   = o_down16 + (size_t)NEXP * HDIM * IDIM * 2;       // 49,872,896

  char* ws = (char*)d_ws;
  Meta*  meta       = (Meta*)ws;
  int*   slot_token = (int*)(ws + 4096);     // 5120*4 -> ends 24,576
  float* slot_w     = (float*)(ws + 24576);  // 5120*4 -> ends 45,056
  u16*   hs16       = (u16*)(ws + o_hs16);
  u16*   hbuf       = (u16*)(ws + o_hbuf);
  u16*   gup16      = (u16*)(ws + o_gup16);
  u16*   down16     = (u16*)(ws + o_down16);

  if (ws_size < needed) return;

  prep_k<<<1025, 256, 0, stream>>>(hs, gup, down, topk, tw,
                                   hs16, gup16, down16, meta, slot_token, slot_w, out);
  gemm1_k<<<MAX_TILES * 6, 512, 0, stream>>>(hs16, gup16, meta, slot_token, slot_w, hbuf);
  gemm2_k<<<MAX_TILES * 8, 512, 0, stream>>>(hbuf, down16, meta, slot_token, out);
}